// Round 9
// baseline (80.357 us; speedup 1.0000x reference)
//
#include <hip/hip_runtime.h>
#include <hip/hip_bf16.h>

typedef __attribute__((ext_vector_type(8))) short short8;   // 8 bf16 MFMA A/B frag
typedef __attribute__((ext_vector_type(4))) float fv4;      // MFMA C/D frag
typedef __attribute__((ext_vector_type(4))) int   iv4;      // 16B pack

constexpr int B_ = 16, A_ = 1024, V_ = 1024, D_ = 512;

__device__ __forceinline__ unsigned cvtpk(float lo, float hi) {
    unsigned r;
    asm("v_cvt_pk_bf16_f32 %0, %1, %2" : "=v"(r) : "v"(lo), "v"(hi));
    return r;
}
#define SB0() __builtin_amdgcn_sched_barrier(0)

__device__ __forceinline__ float sq16(const fv4* v) {
    float s = 0.f;
#pragma unroll
    for (int i = 0; i < 4; ++i)
#pragma unroll
        for (int k = 0; k < 4; ++k) s += v[i][k] * v[i][k];
    return s;
}

// Resident-A fused L2-distance kernel.
// 256 blocks = 16 batches x 8 A-tiles(128 rows) x 2 V-halves(512 cols); 1 block/CU.
// A-panel 128x512 bf16 RESIDENT in LDS (materialized lazily during V-tile 0);
// V streamed as 128x32 double-buffered slices (reg-staged, converted in flight);
// C written per V-tile (4 x 64KB, spread across the kernel). 64-step inner loop.
__global__ void __launch_bounds__(256, 1)
l2res(const float* __restrict__ audio, const float* __restrict__ visual,
      float* __restrict__ out)
{
    __shared__ __align__(16) char sA[128 * 1040];     // 128 rows x (512+8 pad) bf16
    __shared__ __align__(16) char sV[2 * 128 * 80];   // dbuf x 128 rows x (32+8 pad) bf16
    __shared__ float nA[128];
    __shared__ float nV[128];

    const int t = threadIdx.x, lane = t & 63, w = t >> 6;
    const int wm = w >> 1, wn = w & 1;                // wave C-slab 64x64 within 128x128
    const int srow = t >> 1, shalf = t & 1;           // staging: row 0..127, 16-float half

    // XCD-clustered mapping (RR dispatch: XCD = orig%8). XCD x owns batches
    // 2x,2x+1; each (batch,V-half) 8-block group + A-pairs co-resident -> L2 reuse.
    const int orig = blockIdx.x;
    const int x = orig & 7, j = orig >> 3;            // j 0..31 within XCD
    const int b  = 2 * x + (j >> 4);
    const int vh = (j >> 3) & 1;
    const int at = j & 7;

    const float* Ag = audio  + ((size_t)b * A_ + at * 128) * D_;
    const float* Vg = visual + ((size_t)b * V_ + vh * 512) * D_;

    float psA = 0.f, psV = 0.f;

#define PACKST(S, dstp) do {                                             \
        iv4 _w0, _w1;                                                    \
        _w0[0] = (int)cvtpk(S[0][0], S[0][1]);                           \
        _w0[1] = (int)cvtpk(S[0][2], S[0][3]);                           \
        _w0[2] = (int)cvtpk(S[1][0], S[1][1]);                           \
        _w0[3] = (int)cvtpk(S[1][2], S[1][3]);                           \
        _w1[0] = (int)cvtpk(S[2][0], S[2][1]);                           \
        _w1[1] = (int)cvtpk(S[2][2], S[2][3]);                           \
        _w1[2] = (int)cvtpk(S[3][0], S[3][1]);                           \
        _w1[3] = (int)cvtpk(S[3][2], S[3][3]);                           \
        *(iv4*)(dstp) = _w0; *(iv4*)((dstp) + 16) = _w1;                 \
    } while (0)

#define LD4(dst, p) do { dst[0] = *(const fv4*)(p); dst[1] = *(const fv4*)((p) + 4); \
        dst[2] = *(const fv4*)((p) + 8); dst[3] = *(const fv4*)((p) + 12); } while (0)

    // ---- prologue: stage slice ktG=0 (A kt0 + V vt0/kt0) ----
    {
        fv4 a[4], v[4];
        LD4(a, Ag + (size_t)srow * D_ + shalf * 16);
        LD4(v, Vg + (size_t)srow * D_ + shalf * 16);
        SB0();
        psA += sq16(a);
        PACKST(a, sA + srow * 1040 + shalf * 32);
        psV += sq16(v);
        PACKST(v, sV + srow * 80 + shalf * 32);
    }
    __syncthreads();

    fv4 acc[4][4];
#pragma unroll
    for (int m = 0; m < 4; ++m)
#pragma unroll
        for (int n = 0; n < 4; ++n) acc[m][n] = fv4{0.f, 0.f, 0.f, 0.f};

    const int frow = lane & 15, fg = lane >> 4;

    fv4 stA[4], stV[4];

#pragma unroll 1
    for (int ktG = 0; ktG < 64; ++ktG) {
        const int vt = ktG >> 4, kt = ktG & 15, buf = ktG & 1;
        const bool issue = (ktG < 63);
        const bool lazyA = issue && (ktG + 1 < 16);

        // ---- ISSUE next slice's global loads (full K-step of cover) ----
        if (issue) {
            const int sN = ktG + 1, vtN = sN >> 4, ktN = sN & 15;
            LD4(stV, Vg + ((size_t)(vtN * 128 + srow)) * D_ + ktN * 32 + shalf * 16);
            if (lazyA)
                LD4(stA, Ag + (size_t)srow * D_ + sN * 32 + shalf * 16);
            SB0();
        }

        // ---- compute K-step: 8 ds_read_b128 + 16 MFMA per wave ----
        {
            short8 av[4], bv[4];
#pragma unroll
            for (int m = 0; m < 4; ++m)
                av[m] = *(const short8*)(sA + (wm * 64 + m * 16 + frow) * 1040
                                            + kt * 64 + fg * 16);
#pragma unroll
            for (int n = 0; n < 4; ++n)
                bv[n] = *(const short8*)(sV + buf * 10240
                                            + (wn * 64 + n * 16 + frow) * 80 + fg * 16);
#pragma unroll
            for (int m = 0; m < 4; ++m)
#pragma unroll
                for (int n = 0; n < 4; ++n)
                    acc[m][n] = __builtin_amdgcn_mfma_f32_16x16x32_bf16(
                        av[m], bv[n], acc[m][n], 0, 0, 0);
        }

        // ---- V-tile boundary: norms -> LDS, fused sqrt epilogue, acc reset ----
        if (kt == 15) {
            psV += __shfl_xor(psV, 1, 64);
            if (vt == 0) psA += __shfl_xor(psA, 1, 64);
            __syncthreads();
            if (shalf == 0) {
                nV[srow] = psV;
                if (vt == 0) nA[srow] = psA;
            }
            __syncthreads();

            float* Ob = out + ((size_t)b * A_ + at * 128) * V_ + vh * 512 + vt * 128;
#pragma unroll
            for (int m = 0; m < 4; ++m) {
#pragma unroll
                for (int n = 0; n < 4; ++n) {
                    const int col = wn * 64 + n * 16 + frow;       // C/D: col = lane&15
                    const float vsq = nV[col];
#pragma unroll
                    for (int jj = 0; jj < 4; ++jj) {
                        const int row = wm * 64 + m * 16 + fg * 4 + jj;  // row=(lane>>4)*4+reg
                        float d2 = nA[row] + vsq - 2.f * acc[m][n][jj];
                        Ob[(size_t)row * V_ + col] = sqrtf(fmaxf(d2, 0.f));
                    }
                }
            }
            psV = 0.f;
#pragma unroll
            for (int m = 0; m < 4; ++m)
#pragma unroll
                for (int n = 0; n < 4; ++n) acc[m][n] = fv4{0.f, 0.f, 0.f, 0.f};
        }

        // ---- rotate: done reading sV[buf] (and sA[kt] in vt0); stage next ----
        __syncthreads();
        if (issue) {
            psV += sq16(stV);
            PACKST(stV, sV + (buf ^ 1) * 10240 + srow * 80 + shalf * 32);
            if (lazyA) {
                psA += sq16(stA);
                PACKST(stA, sA + srow * 1040 + (ktG + 1) * 64 + shalf * 32);
            }
        }
        __syncthreads();
    }
#undef PACKST
#undef LD4
}

extern "C" void kernel_launch(void* const* d_in, const int* in_sizes, int n_in,
                              void* d_out, int out_size, void* d_ws, size_t ws_size,
                              hipStream_t stream) {
    const float* audio  = (const float*)d_in[0];
    const float* visual = (const float*)d_in[1];
    float* out = (float*)d_out;
    l2res<<<256, 256, 0, stream>>>(audio, visual, out);
}

// Round 10
// 49.488 us; speedup vs baseline: 1.6238x; 1.6238x over previous
//
#include <hip/hip_runtime.h>
#include <hip/hip_bf16.h>

typedef __attribute__((ext_vector_type(8))) short short8;   // 8 bf16 MFMA A/B frag
typedef __attribute__((ext_vector_type(4))) float fv4;      // MFMA C/D frag
typedef __attribute__((ext_vector_type(4))) int   iv4;      // 16B pack

constexpr int B_ = 16, A_ = 1024, V_ = 1024, D_ = 512;
constexpr int ROWS_A = B_ * A_;              // 16384
constexpr int ROWS_T = 2 * ROWS_A;           // 32768
constexpr size_t BF_ONE = (size_t)ROWS_A * D_ * 2;          // 16 MiB each
constexpr size_t WS_NEED = 2 * BF_ONE + (size_t)ROWS_T * 4; // 32 MiB + 128 KiB

// fp32 -> bf16 round-to-nearest-even
__device__ __forceinline__ unsigned f2bf(float f) {
    unsigned u = __builtin_bit_cast(unsigned, f);
    return (u + 0x7fffu + ((u >> 16) & 1u)) >> 16;
}

// ---------------- Pass 1: fp32 -> bf16 convert + row squared-norms ----------------
__global__ void __launch_bounds__(256)
convert_kernel(const float* __restrict__ audio, const float* __restrict__ visual,
               ushort* __restrict__ abf, ushort* __restrict__ vbf,
               float* __restrict__ normA, float* __restrict__ normV)
{
    const int lane = threadIdx.x & 63;
    const int wv   = (blockIdx.x * 256 + threadIdx.x) >> 6;
    const int nw   = (gridDim.x * 256) >> 6;

    for (int row = wv; row < ROWS_T; row += nw) {
        const float* src; ushort* dst; float* nd; int r;
        if (row < ROWS_A) { src = audio;  dst = abf; nd = normA; r = row; }
        else              { src = visual; dst = vbf; nd = normV; r = row - ROWS_A; }

        const float* p = src + (size_t)r * D_ + lane * 8;   // one wave = one row
        fv4 x0 = *(const fv4*)p;
        fv4 x1 = *(const fv4*)(p + 4);

        float s = 0.f;
#pragma unroll
        for (int i = 0; i < 4; ++i) s += x0[i] * x0[i] + x1[i] * x1[i];

        iv4 w;
        w[0] = (int)(f2bf(x0[0]) | (f2bf(x0[1]) << 16));
        w[1] = (int)(f2bf(x0[2]) | (f2bf(x0[3]) << 16));
        w[2] = (int)(f2bf(x1[0]) | (f2bf(x1[1]) << 16));
        w[3] = (int)(f2bf(x1[2]) | (f2bf(x1[3]) << 16));
        *(iv4*)(dst + (size_t)r * D_ + lane * 8) = w;

#pragma unroll
        for (int m = 1; m < 64; m <<= 1) s += __shfl_xor(s, m, 64);
        if (lane == 0) nd[r] = s;
    }
}

// ---------------- raw-primitive helpers ----------------
__device__ __forceinline__ void gload16(const void* g, void* l) {
    __builtin_amdgcn_global_load_lds((const __attribute__((address_space(1))) void*)g,
                                     (__attribute__((address_space(3))) void*)l,
                                     16, 0, 0);
}
__device__ __forceinline__ unsigned lds_addr(const void* p) {
    return (unsigned)(unsigned long long)(__attribute__((address_space(3))) const char*)p;
}
__device__ __forceinline__ short8 dsr128(unsigned a) {
    short8 r;
    asm volatile("ds_read_b128 %0, %1" : "=v"(r) : "v"(a));
    return r;
}
#define SB0()   __builtin_amdgcn_sched_barrier(0)
#define LGK0()  asm volatile("s_waitcnt lgkmcnt(0)")
#define VMCN(n) asm volatile("s_waitcnt vmcnt(" #n ")")
#define RBAR()  do { SB0(); __builtin_amdgcn_s_barrier(); SB0(); } while (0)

// ---------------- Pass 2: 256x256 bf16 GEMM, depth-2 counted-vmcnt pipeline ----------------
// 512 threads = 8 waves (2M x 4N; per-wave C = 128x64 = 8x4 frags). BK=64, 8 K-tiles.
// LDS: 2 x (A 256x64 + B 256x64) bf16 = 128 KiB; linear gload_lds dest with
// inverse-swizzled global source (proven 0-conflict in rounds 2-3).
// Loop: VMCN(8) [K(t) landed, K(t+1) in flight]; BAR; 4 compute phases;
//       BAR; STAGE K(t+2) into the buffer just freed. vmcnt never drains to 0.
__global__ void __launch_bounds__(512, 1)
gemm256(const ushort* __restrict__ abf, const ushort* __restrict__ vbf,
        const float* __restrict__ normA, const float* __restrict__ normV,
        float* __restrict__ out)
{
    __shared__ __align__(16) char sA[2][256 * 128];
    __shared__ __align__(16) char sB[2][256 * 128];
    __shared__ float lnrm[512];

    const int t = threadIdx.x, lane = t & 63, w = t >> 6;
    const int wm = w >> 2, wn = w & 3;

    // XCD-bijective swizzle: 256 blocks; each XCD gets 32 = 2 whole batches.
    const int orig = blockIdx.x;
    const int wg   = (orig & 7) * 32 + (orig >> 3);
    const int b = wg >> 4, tile = wg & 15, ab = tile >> 2, vb = tile & 3;

    const ushort* Ag = abf + ((size_t)b * A_ + ab * 256) * D_;
    const ushort* Vg = vbf + ((size_t)b * V_ + vb * 256) * D_;

    // staging: per gload16 a wave covers 8 rows x 128 B; source pre-swizzled
    const int rl = lane >> 3;            // dest row within 8-row group
    const int cs = (lane & 7) ^ rl;      // swizzled source chunk (involution)
    const ushort* asrc = Ag + (size_t)(w * 8 + rl) * D_ + cs * 8;
    const ushort* vsrc = Vg + (size_t)(w * 8 + rl) * D_ + cs * 8;

    // wave w stages A rows {w*8+[0,8), +64, +128, +192} and same B rows: 8 loads
#define STAGE(kt, buf) do {                                               \
        const size_t _ko = (size_t)(kt) * 64;                             \
        char* _da = (char*)sA[buf] + w * 8 * 128;                         \
        char* _db = (char*)sB[buf] + w * 8 * 128;                         \
        gload16(asrc + 0 * 64 * D_ + _ko, _da + 0 * 64 * 128);            \
        gload16(vsrc + 0 * 64 * D_ + _ko, _db + 0 * 64 * 128);            \
        gload16(asrc + 1 * 64 * D_ + _ko, _da + 1 * 64 * 128);            \
        gload16(vsrc + 1 * 64 * D_ + _ko, _db + 1 * 64 * 128);            \
        gload16(asrc + 2 * 64 * D_ + _ko, _da + 2 * 64 * 128);            \
        gload16(vsrc + 2 * 64 * D_ + _ko, _db + 2 * 64 * 128);            \
        gload16(asrc + 3 * 64 * D_ + _ko, _da + 3 * 64 * 128);            \
        gload16(vsrc + 3 * 64 * D_ + _ko, _db + 3 * 64 * 128);            \
    } while (0)

    // norms -> LDS (plain sync, before the pipeline starts)
    if (t < 256) lnrm[t] = normA[(size_t)b * A_ + ab * 256 + t];
    else         lnrm[t] = normV[(size_t)b * V_ + vb * 256 + (t - 256)];
    __syncthreads();

    // ---- prologue: stage K0 and K1 (16 loads in flight) ----
    STAGE(0, 0);
    STAGE(1, 1);

    fv4 acc[8][4];
#pragma unroll
    for (int m = 0; m < 8; ++m)
#pragma unroll
        for (int n = 0; n < 4; ++n) acc[m][n] = fv4{0.f, 0.f, 0.f, 0.f};

    const int frow = lane & 15, fg = lane >> 4, xk = frow & 7;
    const unsigned cof0 = (unsigned)(((0 + fg) ^ xk) << 4);   // k-half 0 chunk
    const unsigned cof1 = (unsigned)(((4 + fg) ^ xk) << 4);   // k-half 1
    const unsigned baseA = lds_addr(&sA[0][0]);
    const unsigned baseB = lds_addr(&sB[0][0]);
    const unsigned arow = (unsigned)((wm * 128 + frow) * 128);
    const unsigned brow = (unsigned)((wn * 64 + frow) * 128);

    short8 av[4][2], bv[4][2];

#pragma unroll 1
    for (int kt = 0; kt < 8; ++kt) {
        const int cur = kt & 1;
        const unsigned Ab = baseA + (unsigned)cur * 32768u + arow;
        const unsigned Bb = baseB + (unsigned)cur * 32768u + brow;

        // K(kt)'s 8 loads landed (K(kt+1)'s 8 may remain in flight)
        if (kt < 7) { VMCN(8); } else { VMCN(0); }
        RBAR();

        // ---- phase 0: A m0-3 (8 reads) + B n0-1 (4 reads); 16 MFMA ----
#pragma unroll
        for (int m = 0; m < 4; ++m) {
            av[m][0] = dsr128(Ab + m * 2048 + cof0);
            av[m][1] = dsr128(Ab + m * 2048 + cof1);
        }
#pragma unroll
        for (int n = 0; n < 2; ++n) {
            bv[n][0] = dsr128(Bb + n * 2048 + cof0);
            bv[n][1] = dsr128(Bb + n * 2048 + cof1);
        }
        LGK0(); SB0();
        __builtin_amdgcn_s_setprio(1);
#pragma unroll
        for (int k = 0; k < 2; ++k)
#pragma unroll
            for (int m = 0; m < 4; ++m)
#pragma unroll
                for (int n = 0; n < 2; ++n)
                    acc[m][n] = __builtin_amdgcn_mfma_f32_16x16x32_bf16(av[m][k], bv[n][k], acc[m][n], 0, 0, 0);
        __builtin_amdgcn_s_setprio(0);

        // ---- phase 1: B n2-3 (4 reads); 16 MFMA (reuse A m0-3) ----
#pragma unroll
        for (int n = 2; n < 4; ++n) {
            bv[n][0] = dsr128(Bb + n * 2048 + cof0);
            bv[n][1] = dsr128(Bb + n * 2048 + cof1);
        }
        LGK0(); SB0();
        __builtin_amdgcn_s_setprio(1);
#pragma unroll
        for (int k = 0; k < 2; ++k)
#pragma unroll
            for (int m = 0; m < 4; ++m)
#pragma unroll
                for (int n = 2; n < 4; ++n)
                    acc[m][n] = __builtin_amdgcn_mfma_f32_16x16x32_bf16(av[m][k], bv[n][k], acc[m][n], 0, 0, 0);
        __builtin_amdgcn_s_setprio(0);

        // ---- phase 2: A m4-7 (8 reads); 16 MFMA (reuse B n2-3) ----
#pragma unroll
        for (int m = 0; m < 4; ++m) {
            av[m][0] = dsr128(Ab + (m + 4) * 2048 + cof0);
            av[m][1] = dsr128(Ab + (m + 4) * 2048 + cof1);
        }
        LGK0(); SB0();
        __builtin_amdgcn_s_setprio(1);
#pragma unroll
        for (int k = 0; k < 2; ++k)
#pragma unroll
            for (int m = 0; m < 4; ++m)
#pragma unroll
                for (int n = 2; n < 4; ++n)
                    acc[m + 4][n] = __builtin_amdgcn_mfma_f32_16x16x32_bf16(av[m][k], bv[n][k], acc[m + 4][n], 0, 0, 0);
        __builtin_amdgcn_s_setprio(0);

        // ---- phase 3: no reads; 16 MFMA (reuse A m4-7, B n0-1) ----
        __builtin_amdgcn_s_setprio(1);
#pragma unroll
        for (int k = 0; k < 2; ++k)
#pragma unroll
            for (int m = 0; m < 4; ++m)
#pragma unroll
                for (int n = 0; n < 2; ++n)
                    acc[m + 4][n] = __builtin_amdgcn_mfma_f32_16x16x32_bf16(av[m][k], bv[n][k], acc[m + 4][n], 0, 0, 0);
        __builtin_amdgcn_s_setprio(0);

        RBAR();   // all waves done READING buf[cur]
        if (kt < 6) STAGE(kt + 2, cur);   // refill freed buffer; stays in flight
    }

    // ---- fused epilogue: out = sqrt(max(||a||^2 + ||v||^2 - 2*cross, 0)) ----
    float* Ob = out + (size_t)b * A_ * V_ + (size_t)(ab * 256) * V_ + vb * 256;
#pragma unroll
    for (int m = 0; m < 8; ++m) {
#pragma unroll
        for (int n = 0; n < 4; ++n) {
            const int col = wn * 64 + n * 16 + frow;      // C/D: col = lane&15
            const float vsq = lnrm[256 + col];
#pragma unroll
            for (int j = 0; j < 4; ++j) {
                const int row = wm * 128 + m * 16 + fg * 4 + j;  // row=(lane>>4)*4+reg
                float d2 = lnrm[row] + vsq - 2.f * acc[m][n][j];
                Ob[(size_t)row * V_ + col] = sqrtf(fmaxf(d2, 0.f));
            }
        }
    }
#undef STAGE
}

// ---------------- Fallback (ws too small): naive fp32, correct but slow ----------------
__global__ void __launch_bounds__(256)
l2dist_naive(const float* __restrict__ audio, const float* __restrict__ visual,
             float* __restrict__ out)
{
    const size_t idx = (size_t)blockIdx.x * 256 + threadIdx.x;
    const size_t total = (size_t)B_ * A_ * V_;
    if (idx >= total) return;
    const int v = idx & (V_ - 1);
    const int a = (idx >> 10) & (A_ - 1);
    const int b = idx >> 20;
    const float* ap = audio  + ((size_t)b * A_ + a) * D_;
    const float* vp = visual + ((size_t)b * V_ + v) * D_;
    float s = 0.f;
    for (int d = 0; d < D_; ++d) {
        float df = ap[d] - vp[d];
        s += df * df;
    }
    out[idx] = sqrtf(s);
}

extern "C" void kernel_launch(void* const* d_in, const int* in_sizes, int n_in,
                              void* d_out, int out_size, void* d_ws, size_t ws_size,
                              hipStream_t stream) {
    const float* audio  = (const float*)d_in[0];
    const float* visual = (const float*)d_in[1];
    float* out = (float*)d_out;

    if (ws_size >= WS_NEED) {
        char* ws = (char*)d_ws;
        ushort* abf = (ushort*)ws;
        ushort* vbf = (ushort*)(ws + BF_ONE);
        float*  nA  = (float*)(ws + 2 * BF_ONE);
        float*  nV  = nA + ROWS_A;
        convert_kernel<<<2048, 256, 0, stream>>>(audio, visual, abf, vbf, nA, nV);
        gemm256<<<256, 512, 0, stream>>>(abf, vbf, nA, nV, out);
    } else {
        const size_t total = (size_t)B_ * A_ * V_;
        l2dist_naive<<<(int)((total + 255) / 256), 256, 0, stream>>>(audio, visual, out);
    }
}